// Round 5
// baseline (99.088 us; speedup 1.0000x reference)
//
#include <hip/hip_runtime.h>

#define HH 1024
#define WW 1024
#define KK 9
#define PADK 4
#define BW 64               // pixels per block: one 64-px segment of an image row
#define TCOL (BW + 2*PADK)  // 72
#define NW 81

// Wave-autonomous KPN: block = 1 wave = 64 consecutive pixels of one image row.
// The block's 64x81 weights are contiguous in cnn (20736 B, 16B-aligned) ->
// staged via 20x global_load_lds width=16 + 1x width=4, linear LDS dst
// (wave-uniform base + lane*16: the DMA layout rule), linear global src.
// No barriers anywhere: single wave + one counted s_waitcnt. 31 KB LDS ->
// 5 blocks/CU; each resident wave keeps 20.7 KB of DMA in flight, so HBM
// stays saturated while other waves compute (stage/compute phases of the 5
// resident blocks interleave instead of round-2's lockstep barrier drain).
__global__ __launch_bounds__(64) void denoiser_kpn(
    const float* __restrict__ unet, const float* __restrict__ cnn,
    float* __restrict__ out) {
  __shared__ float4 tile[KK][TCOL];  // 9 x 72 x 16 B = 10368 B (reflect-padded)
  __shared__ float wlds[BW * NW];    // [pixel][81], 20736 B

  const int lane = threadIdx.x;  // 0..63
  const int bx = blockIdx.x;     // 0..15
  const int py = blockIdx.y;     // 0..1023
  const int px0 = bx * BW;

  // ---- 1. Issue weight DMA first: 20736 contiguous bytes. ----
  // dst = base + lane*16 (linear), src = same linear offsets -> each
  // instruction moves 1024 contiguous bytes; imm-offset addressing, ~0 VALU.
  {
    const char* s = (const char*)(cnn + ((size_t)py * WW + px0) * NW);
    char* d = (char*)wlds;
#pragma unroll
    for (int i = 0; i < 20; ++i) {
      __builtin_amdgcn_global_load_lds(
          (const __attribute__((address_space(1))) unsigned int*)(s + i * 1024 + lane * 16),
          (__attribute__((address_space(3))) unsigned int*)(d + i * 1024 + lane * 16),
          16, 0, 0);
    }
    __builtin_amdgcn_global_load_lds(
        (const __attribute__((address_space(1))) unsigned int*)(s + 20480 + lane * 4),
        (__attribute__((address_space(3))) unsigned int*)(d + 20480 + lane * 4),
        4, 0, 0);
  }

  // ---- 2. Stage 9x72 reflect-padded unet tile (L2/L3-resident reads). ----
  for (int idx = lane; idx < KK * TCOL; idx += 64) {
    const int r = idx / TCOL;
    const int c = idx - r * TCOL;
    int gy = py - PADK + r;
    gy = gy < 0 ? -gy : (gy >= HH ? 2 * HH - 2 - gy : gy);
    int gx = px0 - PADK + c;
    gx = gx < 0 ? -gx : (gx >= WW ? 2 * WW - 2 - gx : gx);
    const float* p = unet + ((size_t)gy * WW + gx) * 3;
    ((float4*)tile)[idx] = make_float4(p[0], p[1], p[2], 0.0f);
  }

  // ---- 3. Single wave: one wait, no barrier. ----
  asm volatile("s_waitcnt vmcnt(0) lgkmcnt(0)" ::: "memory");
  __builtin_amdgcn_sched_barrier(0);

  // ---- 4. 81 taps: ds_read_b128 (uniform 8/bank = b128 minimum) +
  //         ds_read_b32 (lane stride 324 B -> 2-way = free) + 3 FMA. ----
  float ax = 0.0f, ay = 0.0f, az = 0.0f;
  const float* wrow = wlds + lane * NW;
#pragma unroll
  for (int ki = 0; ki < KK; ++ki) {
#pragma unroll
    for (int kj = 0; kj < KK; ++kj) {
      const float4 pv = tile[ki][lane + kj];
      const float w = wrow[ki * KK + kj];
      ax = fmaf(w, pv.x, ax);
      ay = fmaf(w, pv.y, ay);
      az = fmaf(w, pv.z, az);
    }
  }

  float* o = out + ((size_t)py * WW + px0 + lane) * 3;
  o[0] = ax;
  o[1] = ay;
  o[2] = az;
}

extern "C" void kernel_launch(void* const* d_in, const int* in_sizes, int n_in,
                              void* d_out, int out_size, void* d_ws, size_t ws_size,
                              hipStream_t stream) {
  const float* unet = (const float*)d_in[0];  // [1024,1024,3] f32
  const float* cnn = (const float*)d_in[1];   // [1024,1024,81] f32
  float* out = (float*)d_out;                 // [1024,1024,3] f32
  dim3 grid(WW / BW, HH);                     // 16 x 1024 = 16384 wave-blocks
  dim3 block(BW);
  denoiser_kpn<<<grid, block, 0, stream>>>(unet, cnn, out);
}